// Round 1
// baseline (666.847 us; speedup 1.0000x reference)
//
#include <hip/hip_runtime.h>

#define NUM_WORDS 31995
#define DIM 128
#define LATENT 10000
#define TOTAL_NGRAMS 639900
#define VOCAB 32000

typedef __attribute__((ext_vector_type(8))) short bf16x8;
typedef __attribute__((ext_vector_type(4))) float f32x4;

__device__ __forceinline__ unsigned short f2b(float f){
  union { float f; unsigned int u; } a; a.f = f;
  unsigned int r = (a.u + 0x7fffu + ((a.u >> 16) & 1u)) >> 16;
  return (unsigned short)r;
}

// ---- Kernel A: segment start offsets via binary search (segment_ids sorted) ----
__global__ void k_starts(const int* __restrict__ seg, int* __restrict__ starts){
  int w = blockIdx.x * blockDim.x + threadIdx.x;
  if (w > NUM_WORDS) return;
  int lo = 0, hi = TOTAL_NGRAMS;
  while (lo < hi){ int mid = (lo + hi) >> 1; if (seg[mid] < w) lo = mid + 1; else hi = mid; }
  starts[w] = lo;
}

// ---- Kernel B: ragged mean-pool + tanh -> emb_weight rows (f32) + bf16 Q copy ----
__global__ void k_bag(const int* __restrict__ ngram_ids, const float* __restrict__ table,
                      const int* __restrict__ starts, float* __restrict__ embw,
                      unsigned short* __restrict__ langbf){
  int w = blockIdx.x; int d = threadIdx.x;
  if (w >= NUM_WORDS){ langbf[w*DIM + d] = 0; return; }   // pad rows 31995..31999: zero Q
  int s = starts[w], e = starts[w+1];
  float acc = 0.f;
  for (int t = s; t < e; ++t)
    acc += table[(long)ngram_ids[t]*DIM + d];
  float val = 0.f; int c = e - s;
  if (c > 0) val = tanhf(acc / (float)c);
  embw[(long)(4+w)*DIM + d] = val;
  langbf[w*DIM + d] = f2b(val);
}

// ---- Kernel C: flash attention  emb_weight[4+q] += softmax(Q K^T) V ----
// Q = lang_emb (bf16), K = V = latent_mat. 4 waves/block, 16 q-rows per wave,
// L-tiles of 64. mfma_f32_16x16x32_bf16; C/D layout: col=lane&15, row=(lane>>4)*4+r.
__global__ __launch_bounds__(256, 2) void k_flash(const unsigned short* __restrict__ langbf,
                       const float* __restrict__ latent, float* __restrict__ embw){
  __shared__ unsigned short Klds[64*128];     // [lrow][d], 16B-block XOR swizzle by lrow&7
  __shared__ unsigned short Vt[128*68];       // [d][lrow], stride 68 (pad 4) -> b64 reads
  __shared__ unsigned short Plds[4][16*72];   // per-wave P tile [16][64], stride 72

  const int tid = threadIdx.x;
  const int wv  = tid >> 6;
  const int l   = tid & 63;
  const int lm  = l & 15;
  const int lg  = l >> 4;

  // Q fragments (A-operand): row = lane&15, k = (lane>>4)*8 + i (contiguous)
  const int qrow = blockIdx.x*64 + wv*16 + lm;
  bf16x8 qf[4];
  #pragma unroll
  for (int ks = 0; ks < 4; ++ks)
    qf[ks] = *(const bf16x8*)(langbf + (long)qrow*DIM + ks*32 + lg*8);

  f32x4 oacc[8];
  #pragma unroll
  for (int i = 0; i < 8; ++i) oacc[i] = (f32x4){0.f,0.f,0.f,0.f};
  float m_r[4], s_r[4];
  #pragma unroll
  for (int r = 0; r < 4; ++r){ m_r[r] = -1e30f; s_r[r] = 0.f; }

  const int NT = (LATENT + 63)/64;            // 157 (last tile: 16 valid)
  for (int t = 0; t < NT; ++t){
    const int l0 = t*64;
    __syncthreads();                          // prior tile's reads done before overwrite
    // stage 64x128 latent tile -> bf16 K (swizzled) and V^T (padded)
    #pragma unroll
    for (int k = 0; k < 16; ++k){
      int p  = k*256 + tid;                   // pair index, 4096 pairs
      int rr = p >> 6;
      int d  = (p & 63)*2;
      int lrow = l0 + rr;
      float x0 = 0.f, x1 = 0.f;
      if (lrow < LATENT){
        const float* src = latent + (long)lrow*DIM + d;
        x0 = src[0]; x1 = src[1];
      }
      unsigned short b0 = f2b(x0), b1 = f2b(x1);
      int blk = (d >> 3) ^ (rr & 7);
      unsigned int packed = (unsigned int)b0 | ((unsigned int)b1 << 16);
      *(unsigned int*)&Klds[rr*128 + blk*8 + (d & 7)] = packed;
      Vt[d*68 + rr]     = b0;
      Vt[(d+1)*68 + rr] = b1;
    }
    __syncthreads();

    // S = Q K^T : 4 col-blocks x 4 k-steps
    f32x4 sacc[4];
    #pragma unroll
    for (int n = 0; n < 4; ++n){
      sacc[n] = (f32x4){0.f,0.f,0.f,0.f};
      int col = n*16 + lm;
      #pragma unroll
      for (int ks = 0; ks < 4; ++ks){
        int blk = (ks*4 + lg) ^ (col & 7);
        bf16x8 kf = *(const bf16x8*)&Klds[col*128 + blk*8];
        sacc[n] = __builtin_amdgcn_mfma_f32_16x16x32_bf16(qf[ks], kf, sacc[n], 0, 0, 0);
      }
      if (l0 + col >= LATENT)                 // tail mask -> -inf
        sacc[n] = (f32x4){-1e30f,-1e30f,-1e30f,-1e30f};
    }

    // online softmax per row (row r lives in the 16 lanes sharing lg)
    float pv[4][4]; float scale[4];
    #pragma unroll
    for (int r = 0; r < 4; ++r){
      float mx = fmaxf(fmaxf(sacc[0][r], sacc[1][r]), fmaxf(sacc[2][r], sacc[3][r]));
      #pragma unroll
      for (int off = 1; off < 16; off <<= 1) mx = fmaxf(mx, __shfl_xor(mx, off, 64));
      float mnew = fmaxf(m_r[r], mx);
      float sc = __expf(m_r[r] - mnew);
      float rs = 0.f;
      #pragma unroll
      for (int n = 0; n < 4; ++n){
        float p = __expf(sacc[n][r] - mnew);
        pv[n][r] = p; rs += p;
      }
      #pragma unroll
      for (int off = 1; off < 16; off <<= 1) rs += __shfl_xor(rs, off, 64);
      s_r[r] = s_r[r]*sc + rs;
      m_r[r] = mnew;
      scale[r] = sc;
    }
    #pragma unroll
    for (int nd = 0; nd < 8; ++nd)
      #pragma unroll
      for (int r = 0; r < 4; ++r) oacc[nd][r] *= scale[r];

    // P: C-layout -> LDS -> A-layout (per-wave buffer, no barrier needed)
    #pragma unroll
    for (int n = 0; n < 4; ++n)
      #pragma unroll
      for (int r = 0; r < 4; ++r)
        Plds[wv][(lg*4+r)*72 + n*16 + lm] = f2b(pv[n][r]);

    // O += P V : 8 d-blocks x 2 k-steps
    #pragma unroll
    for (int ks = 0; ks < 2; ++ks){
      bf16x8 pf = *(const bf16x8*)&Plds[wv][lm*72 + ks*32 + lg*8];
      #pragma unroll
      for (int nd = 0; nd < 8; ++nd){
        int dcol = nd*16 + lm;
        union { bf16x8 v; short4 h[2]; } u;
        const unsigned short* vp = &Vt[dcol*68 + ks*32 + lg*8];
        u.h[0] = *(const short4*)vp;
        u.h[1] = *(const short4*)(vp + 4);
        oacc[nd] = __builtin_amdgcn_mfma_f32_16x16x32_bf16(pf, u.v, oacc[nd], 0, 0, 0);
      }
    }
  }

  // epilogue: emb_weight[4+q] += latent_emb
  #pragma unroll
  for (int nd = 0; nd < 8; ++nd){
    #pragma unroll
    for (int r = 0; r < 4; ++r){
      int q = blockIdx.x*64 + wv*16 + lg*4 + r;
      if (q < NUM_WORDS){
        float* dst = embw + (long)(4+q)*DIM + nd*16 + lm;
        *dst += oacc[nd][r] / s_r[r];
      }
    }
  }
}

// ---- Kernel D: special rows 0..3 and mask row 31999 ----
__global__ void k_special(const float* __restrict__ sp, const float* __restrict__ maskemb,
                          float* __restrict__ embw){
  int d = threadIdx.x; int r = blockIdx.x;
  if (r < 4) embw[r*DIM + d] = sp[r*DIM + d];
  else       embw[(long)(VOCAB-1)*DIM + d] = maskemb[d];
}

// ---- Kernel E: out = emb_weight[x] ----
__global__ void k_gather(const int* __restrict__ x, const float* __restrict__ embw,
                         float* __restrict__ out){
  int i = blockIdx.x*256 + threadIdx.x;     // float4 index
  int tok = i >> 5;                         // 32 float4 per token
  int d4  = i & 31;
  float4 v = ((const float4*)embw)[(long)x[tok]*32 + d4];
  ((float4*)out)[i] = v;
}

extern "C" void kernel_launch(void* const* d_in, const int* in_sizes, int n_in,
                              void* d_out, int out_size, void* d_ws, size_t ws_size,
                              hipStream_t stream){
  const int*   x         = (const int*)d_in[0];
  const int*   ngram_ids = (const int*)d_in[1];
  const int*   seg       = (const int*)d_in[2];
  const float* table     = (const float*)d_in[3];
  const float* latent    = (const float*)d_in[4];
  const float* special   = (const float*)d_in[5];
  const float* maskemb   = (const float*)d_in[6];
  float* out = (float*)d_out;

  char* ws = (char*)d_ws;
  int* starts             = (int*)ws;                          // 128,000 B (pad to 131072)
  unsigned short* langbf  = (unsigned short*)(ws + 131072);    // 32000*128*2 = 8,192,000 B
  float* embw             = (float*)(ws + 131072 + 8192000);   // 32000*128*4 = 16,384,000 B

  k_starts <<<(NUM_WORDS + 1 + 255)/256, 256, 0, stream>>>(seg, starts);
  k_bag    <<<VOCAB, DIM, 0, stream>>>(ngram_ids, table, starts, embw, langbf);
  k_special<<<5, DIM, 0, stream>>>(special, maskemb, embw);
  k_flash  <<<VOCAB/64, 256, 0, stream>>>(langbf, latent, embw);
  k_gather <<<(8*512*DIM/4)/256, 256, 0, stream>>>(x, embw, out);
}

// Round 2
// 461.443 us; speedup vs baseline: 1.4451x; 1.4451x over previous
//
#include <hip/hip_runtime.h>

#define NUM_WORDS 31995
#define DIM 128
#define LATENT 10000
#define LPAD 10048
#define NT 157          // LPAD/64
#define TOTAL_NGRAMS 639900
#define VOCAB 32000

typedef __attribute__((ext_vector_type(8))) short bf16x8;
typedef __attribute__((ext_vector_type(4))) float f32x4;
typedef __attribute__((ext_vector_type(8))) unsigned short u16x8;
typedef __attribute__((ext_vector_type(4))) short s16x4;

__device__ __forceinline__ unsigned short f2b(float f){
  union { float f; unsigned int u; } a; a.f = f;
  unsigned int r = (a.u + 0x7fffu + ((a.u >> 16) & 1u)) >> 16;
  return (unsigned short)r;
}

__device__ __forceinline__ void gload16(const void* g, void* l){
  __builtin_amdgcn_global_load_lds(
      (const __attribute__((address_space(1))) unsigned int*)g,
      (__attribute__((address_space(3))) unsigned int*)l, 16, 0, 0);
}

// ---- Kernel A: segment start offsets via binary search (segment_ids sorted) ----
__global__ void k_starts(const int* __restrict__ seg, int* __restrict__ starts){
  int w = blockIdx.x * blockDim.x + threadIdx.x;
  if (w > NUM_WORDS) return;
  int lo = 0, hi = TOTAL_NGRAMS;
  while (lo < hi){ int mid = (lo + hi) >> 1; if (seg[mid] < w) lo = mid + 1; else hi = mid; }
  starts[w] = lo;
}

// ---- Kernel B: ragged mean-pool + tanh -> emb_weight rows (f32) + bf16 Q copy ----
__global__ void k_bag(const int* __restrict__ ngram_ids, const float* __restrict__ table,
                      const int* __restrict__ starts, float* __restrict__ embw,
                      unsigned short* __restrict__ langbf){
  int w = blockIdx.x; int d = threadIdx.x;
  if (w >= NUM_WORDS){ langbf[w*DIM + d] = 0; return; }   // pad rows 31995..31999: zero Q
  int s = starts[w], e = starts[w+1];
  float acc = 0.f;
  for (int t = s; t < e; ++t)
    acc += table[(long)ngram_ids[t]*DIM + d];
  float val = 0.f; int c = e - s;
  if (c > 0) val = tanhf(acc / (float)c);
  embw[(long)(4+w)*DIM + d] = val;
  langbf[w*DIM + d] = f2b(val);
}

// ---- Prep K: latent f32 -> bf16 row-major [LPAD][128], zero-padded ----
__global__ void k_prep_k(const float* __restrict__ latent, unsigned short* __restrict__ Kbf){
  int i = blockIdx.x*256 + threadIdx.x;      // one thread per 8 elems
  if (i >= LPAD*DIM/8) return;
  int base = i*8;
  u16x8 v;
  if (base < LATENT*DIM){
    float4 a = *(const float4*)(latent + base);
    float4 b = *(const float4*)(latent + base + 4);
    v = (u16x8){f2b(a.x),f2b(a.y),f2b(a.z),f2b(a.w),f2b(b.x),f2b(b.y),f2b(b.z),f2b(b.w)};
  } else {
    v = (u16x8){0,0,0,0,0,0,0,0};
  }
  *(u16x8*)(Kbf + base) = v;
}

// ---- Prep V: latent -> bf16 transposed [128][LPAD] via LDS tile transpose ----
__global__ void k_prep_v(const float* __restrict__ latent, unsigned short* __restrict__ VtG){
  __shared__ unsigned short TL[128*66];
  const int l0 = blockIdx.x*64;
  const int tid = threadIdx.x;
  #pragma unroll
  for (int it = 0; it < 32; ++it){
    int idx = it*256 + tid;                  // 8192 elems: 64 l x 128 d
    int lr = idx >> 7, d = idx & 127;
    float x = (l0 + lr < LATENT) ? latent[(size_t)(l0+lr)*DIM + d] : 0.f;
    TL[d*66 + lr] = f2b(x);
  }
  __syncthreads();
  #pragma unroll
  for (int it = 0; it < 8; ++it){
    int idx4 = it*256 + tid;                 // 2048 short4 chunks: 128 d x 16 j
    int d = idx4 >> 4, j = idx4 & 15;
    s16x4 v = (s16x4){ (short)TL[d*66 + j*4], (short)TL[d*66 + j*4 + 1],
                       (short)TL[d*66 + j*4 + 2], (short)TL[d*66 + j*4 + 3] };
    *(s16x4*)(VtG + (size_t)d*LPAD + l0 + j*4) = v;
  }
}

// ---- Kernel C: flash attention (no-max softmax)  emb_weight[4+q] += softmax(QK^T)V ----
// 2 waves/block, 32 q-rows/wave (2 m-subtiles sharing every K/V fragment), l-tiles of 64.
// K/V double-buffered in dynamic LDS, staged by global_load_lds w=16 with XOR-swizzled
// per-lane SOURCE addresses (LDS dest stays linear). exp needs no max: |S| <= ~1.7.
__global__ __launch_bounds__(128, 1) void k_flash(
    const unsigned short* __restrict__ langbf,
    const unsigned short* __restrict__ Kbf,
    const unsigned short* __restrict__ VtG,
    float* __restrict__ embw)
{
  extern __shared__ unsigned short sm[];
  unsigned short* KL = sm;                     // [2][64*128]  rows 256B, 16B blks ^ (row&7)
  unsigned short* VL = sm + 16384;             // [2][128*64]  rows 128B, 16B blks ^ (d&7)
  const int tid = threadIdx.x;
  const int wv  = tid >> 6;
  const int l   = tid & 63;
  const int lm  = l & 15;
  const int lg  = l >> 4;
  unsigned short* PB = sm + 32768 + wv*2304;   // per-wave P [32][72]

  const int qb = blockIdx.x*64 + wv*32;

  // Q fragments (A-operand): row = lane&15, k = (lane>>4)*8 + i
  bf16x8 qf[2][4];
  #pragma unroll
  for (int m = 0; m < 2; ++m)
    #pragma unroll
    for (int ks = 0; ks < 4; ++ks)
      qf[m][ks] = *(const bf16x8*)(langbf + (size_t)(qb + m*16 + lm)*DIM + ks*32 + lg*8);

  // staging lane offsets (loop-invariant)
  int kofs[8], vofs[8];
  #pragma unroll
  for (int j = 0; j < 8; ++j){
    int c   = wv*8 + j;
    int row = c*4 + (l >> 4);
    kofs[j] = row*128 + (((l & 15) ^ (row & 7))*8);
    int d   = c*8 + (l >> 3);
    vofs[j] = d*LPAD + (((l & 7) ^ (d & 7))*8);
  }

  f32x4 oacc[2][8];
  #pragma unroll
  for (int m = 0; m < 2; ++m)
    #pragma unroll
    for (int nd = 0; nd < 8; ++nd) oacc[m][nd] = (f32x4){0.f,0.f,0.f,0.f};
  float s_r[2][4];
  #pragma unroll
  for (int m = 0; m < 2; ++m)
    #pragma unroll
    for (int r = 0; r < 4; ++r) s_r[m][r] = 0.f;

#define STAGE(T, B) do { \
    const unsigned short* kb_ = Kbf + (size_t)(T)*8192; \
    const unsigned short* vb_ = VtG + (T)*64; \
    unsigned short* kl_ = KL + (B)*8192; \
    unsigned short* vl_ = VL + (B)*8192; \
    _Pragma("unroll") \
    for (int j = 0; j < 8; ++j) gload16(kb_ + kofs[j], kl_ + (wv*8+j)*512); \
    _Pragma("unroll") \
    for (int j = 0; j < 8; ++j) gload16(vb_ + vofs[j], vl_ + (wv*8+j)*512); \
  } while(0)

  STAGE(0, 0);
  __syncthreads();

  for (int t = 0; t < NT; ++t){
    const int buf = t & 1;
    if (t + 1 < NT) STAGE(t+1, buf^1);        // issue next-tile loads, no wait
    const unsigned short* Kb = KL + buf*8192;
    const unsigned short* Vb = VL + buf*8192;

    // S = Q K^T (both m-subtiles share every kf fragment)
    f32x4 s0[4], s1[4];
    #pragma unroll
    for (int n = 0; n < 4; ++n){
      s0[n] = (f32x4){0.f,0.f,0.f,0.f};
      s1[n] = (f32x4){0.f,0.f,0.f,0.f};
      const int col = n*16 + lm;
      #pragma unroll
      for (int ks = 0; ks < 4; ++ks){
        bf16x8 kf = *(const bf16x8*)(Kb + col*128 + (((ks*4+lg) ^ (col & 7))*8));
        s0[n] = __builtin_amdgcn_mfma_f32_16x16x32_bf16(qf[0][ks], kf, s0[n], 0, 0, 0);
        s1[n] = __builtin_amdgcn_mfma_f32_16x16x32_bf16(qf[1][ks], kf, s1[n], 0, 0, 0);
      }
    }

    // P = exp(S)  (bounded, no max needed); mask tail cols; per-lane partial sums
    const int l0 = t*64;
    #pragma unroll
    for (int n = 0; n < 4; ++n){
      const bool valid = (l0 + n*16 + lm) < LATENT;
      #pragma unroll
      for (int r = 0; r < 4; ++r){
        float p0 = valid ? __expf(s0[n][r]) : 0.f;
        float p1 = valid ? __expf(s1[n][r]) : 0.f;
        s_r[0][r] += p0; s_r[1][r] += p1;
        PB[(lg*4+r)*72      + n*16 + lm] = f2b(p0);
        PB[(16+lg*4+r)*72   + n*16 + lm] = f2b(p1);
      }
    }

    // O += P V  (vf fragments shared across both m-subtiles)
    #pragma unroll
    for (int ks = 0; ks < 2; ++ks){
      bf16x8 pf0 = *(const bf16x8*)(PB + lm*72      + ks*32 + lg*8);
      bf16x8 pf1 = *(const bf16x8*)(PB + (16+lm)*72 + ks*32 + lg*8);
      #pragma unroll
      for (int nd = 0; nd < 8; ++nd){
        const int dc = nd*16 + lm;
        bf16x8 vf = *(const bf16x8*)(Vb + dc*64 + (((ks*4+lg) ^ (dc & 7))*8));
        oacc[0][nd] = __builtin_amdgcn_mfma_f32_16x16x32_bf16(pf0, vf, oacc[0][nd], 0, 0, 0);
        oacc[1][nd] = __builtin_amdgcn_mfma_f32_16x16x32_bf16(pf1, vf, oacc[1][nd], 0, 0, 0);
      }
    }
    __syncthreads();   // drains vmcnt (stage t+1 landed) + all waves done with buf
  }

  // final row-sum reduce across the 16 lanes sharing lg, then normalize + accumulate
  #pragma unroll
  for (int m = 0; m < 2; ++m)
    #pragma unroll
    for (int r = 0; r < 4; ++r){
      float s = s_r[m][r];
      s += __shfl_xor(s, 1, 64); s += __shfl_xor(s, 2, 64);
      s += __shfl_xor(s, 4, 64); s += __shfl_xor(s, 8, 64);
      s_r[m][r] = 1.f / s;
    }
  #pragma unroll
  for (int m = 0; m < 2; ++m){
    #pragma unroll
    for (int r = 0; r < 4; ++r){
      const int q = qb + m*16 + lg*4 + r;
      if (q < NUM_WORDS){
        const float inv = s_r[m][r];
        float* dst = embw + (size_t)(4+q)*DIM + lm;
        #pragma unroll
        for (int nd = 0; nd < 8; ++nd)
          dst[nd*16] += oacc[m][nd][r] * inv;
      }
    }
  }
#undef STAGE
}

// ---- Kernel D: special rows 0..3 and mask row 31999 ----
__global__ void k_special(const float* __restrict__ sp, const float* __restrict__ maskemb,
                          float* __restrict__ embw){
  int d = threadIdx.x; int r = blockIdx.x;
  if (r < 4) embw[r*DIM + d] = sp[r*DIM + d];
  else       embw[(long)(VOCAB-1)*DIM + d] = maskemb[d];
}

// ---- Kernel E: out = emb_weight[x] ----
__global__ void k_gather(const int* __restrict__ x, const float* __restrict__ embw,
                         float* __restrict__ out){
  int i = blockIdx.x*256 + threadIdx.x;     // float4 index
  int tok = i >> 5;                         // 32 float4 per token
  int d4  = i & 31;
  float4 v = ((const float4*)embw)[(long)x[tok]*32 + d4];
  ((float4*)out)[i] = v;
}

extern "C" void kernel_launch(void* const* d_in, const int* in_sizes, int n_in,
                              void* d_out, int out_size, void* d_ws, size_t ws_size,
                              hipStream_t stream){
  const int*   x         = (const int*)d_in[0];
  const int*   ngram_ids = (const int*)d_in[1];
  const int*   seg       = (const int*)d_in[2];
  const float* table     = (const float*)d_in[3];
  const float* latent    = (const float*)d_in[4];
  const float* special   = (const float*)d_in[5];
  const float* maskemb   = (const float*)d_in[6];
  float* out = (float*)d_out;

  char* ws = (char*)d_ws;
  int* starts            = (int*)ws;                           // 131,072 B
  unsigned short* langbf = (unsigned short*)(ws + 131072);     // 8,192,000 B
  float* embw            = (float*)(ws + 131072 + 8192000);    // 16,384,000 B
  unsigned short* Kbf    = (unsigned short*)(ws + 24707072);   // 2,572,288 B
  unsigned short* VtG    = (unsigned short*)(ws + 27279360);   // 2,572,288 B

  const int SMEM = 2*64*128*2 + 2*128*64*2 + 2*32*72*2;        // 74,752 B
  (void)hipFuncSetAttribute(reinterpret_cast<const void*>(k_flash),
                            hipFuncAttributeMaxDynamicSharedMemorySize, SMEM);

  k_starts <<<(NUM_WORDS + 1 + 255)/256, 256, 0, stream>>>(seg, starts);
  k_prep_k <<<(LPAD*DIM/8 + 255)/256, 256, 0, stream>>>(latent, Kbf);
  k_prep_v <<<NT, 256, 0, stream>>>(latent, VtG);
  k_bag    <<<VOCAB, DIM, 0, stream>>>(ngram_ids, table, starts, embw, langbf);
  k_special<<<5, DIM, 0, stream>>>(special, maskemb, embw);
  k_flash  <<<VOCAB/64, 128, SMEM, stream>>>(langbf, Kbf, VtG, embw);
  k_gather <<<(8*512*DIM/4)/256, 256, 0, stream>>>(x, embw, out);
}